// Round 7
// baseline (203.794 us; speedup 1.0000x reference)
//
#include <hip/hip_runtime.h>
#include <hip/hip_bf16.h>
#include <math.h>

#define NSLICE 2048
#define NH 133     // output spatial size (int(128*1+4)+1)
#define NP 144     // padded to 9 tiles of 16
#define NT 576     // 9 waves per block
#define LDSB 36864 // Tt only, fragment-major: 9 jt x 4 kk x 1024 B

typedef __attribute__((ext_vector_type(8))) short bf16x8;   // 8 bf16 = 4 VGPRs
typedef __attribute__((ext_vector_type(4))) float f32x4;

__device__ __forceinline__ unsigned f2bf(float f) {
    __hip_bfloat16 h = __float2bfloat16(f);   // round-to-nearest-even
    union { __hip_bfloat16 b; unsigned short u; } c; c.b = h; return (unsigned)c.u;
}

// ---------------------------------------------------------------------------
// prep_M: combined (IDCT * mask * DCT) matrices, bf16, in workspace.
//   M[row, p] = sum_{u=0}^{127} D2[u,row] * mask[u] * D1[u,p]
// Rows >= 133 are zero padding. M1 uses rate_weights[0], M2 uses [1].
// ---------------------------------------------------------------------------
__global__ void prep_M(const float* __restrict__ rw,
                       unsigned short* __restrict__ M1,
                       unsigned short* __restrict__ M2) {
    int b   = blockIdx.x;        // 0..287
    int m   = b / NP;            // 0 -> M1 (vertical), 1 -> M2 (horizontal)
    int row = b - m * NP;        // 0..143 (output index i or j)
    int p   = threadIdx.x;       // 0..127 (input index)
    unsigned short* M = (m == 0) ? M1 : M2;

    float val = 0.0f;
    if (row < NH) {
        float r = rw[m];
        float minr = fmaxf((1.0f - 4.0f) / 128.0f, 0.0f);
        r = fminf(fmaxf(r, minr), 2.0f);
        float crop = 128.0f * r;

        const float c1  = (float)(M_PI / 256.0);   // D1 phase period 512
        const float c2  = (float)(M_PI / 266.0);   // D2 phase period 532
        const float s1n = 0.125f;                  // sqrt(2/128)
        const float s10 = 0.08838834764831844f;
        const float s2n = 0.12262786485246718f;    // sqrt(2/133)
        const float s20 = 0.08671099951921386f;

        int tp = 2 * p + 1;
        int ti = 2 * row + 1;
        float acc = 0.0f;
        for (int u = 0; u < 128; ++u) {
            float mask = fminf(fmaxf((4.0f + crop - (float)u) * 0.25f, 0.0f), 1.0f);
            int a1 = (tp * u) & 511;
            int a2 = (ti * u) % 532;
            float d1 = cosf((float)a1 * c1) * ((u == 0) ? s10 : s1n);
            float d2 = cosf((float)a2 * c2) * ((u == 0) ? s20 : s2n);
            acc = fmaf(d1 * mask, d2, acc);
        }
        val = acc;
    }
    M[row * 128 + p] = (unsigned short)f2bf(val);
}

// ---------------------------------------------------------------------------
// dct_resize: one 576-thread block (9 waves) per (b,c) slice. ONE barrier.
//   Stage A: wave w owns j-tile w. Each lane loads its A-fragments straight
//     from global X (fp32, L2-amplified 9x but HBM-unique), converts to bf16
//     in registers, MFMAs against the resident bm2 fragments, and writes the
//     result into Tt in FRAGMENT-MAJOR layout.
//   Tt layout: value (j, p) lives at byte
//       (jt*4 + kk)*1024 + (g*16 + r)*16 + e*2
//     where jt=j>>4, r=j&15, kk=p>>5, g=(p>>3)&3, e=p&7.
//     Stage-B reads are lane-contiguous b128 (conflict-free); stage-A writes
//     land 4 lanes/slot on distinct 128B lines (minimal).
//   Stage B: wave w owns i-tile w; am1 resident; Tt b128 reads; guarded store.
// ---------------------------------------------------------------------------
__global__ __launch_bounds__(NT, 7) void dct_resize(
        const float* __restrict__ x,
        const unsigned short* __restrict__ M1,
        const unsigned short* __restrict__ M2,
        float* __restrict__ out) {
    __shared__ __align__(16) unsigned char lds[LDSB];

    const int tid  = threadIdx.x;
    const int w    = tid >> 6;      // wave 0..8
    const int lane = tid & 63;
    const int r    = lane & 15;     // fragment row/col index
    const int g    = lane >> 4;     // k-group 0..3

    const float* xs = x + (size_t)blockIdx.x * (128 * 128);
    float*       os = out + (size_t)blockIdx.x * (NH * NH);

    const int j0 = w * 16;          // stage A: this wave's j-tile
    const int i0 = w * 16;          // stage B: this wave's i-tile

    // ---- preload loop-invariant M2 fragments (L2-hot, once per wave) ----
    bf16x8 bm2[4];
    #pragma unroll
    for (int kk = 0; kk < 4; ++kk)
        bm2[kk] = *(const bf16x8*)(M2 + (size_t)(j0 + r) * 128 + kk * 32 + g * 8);

    // ---- Stage A ----
    for (int pt = 0; pt < 8; ++pt) {
        const float* xr = xs + (size_t)(pt * 16 + r) * 128;
        float4 xv[8];
        #pragma unroll
        for (int kk = 0; kk < 4; ++kk) {
            xv[2 * kk]     = *(const float4*)(xr + kk * 32 + g * 8);
            xv[2 * kk + 1] = *(const float4*)(xr + kk * 32 + g * 8 + 4);
        }
        f32x4 acc = {0.f, 0.f, 0.f, 0.f};
        #pragma unroll
        for (int kk = 0; kk < 4; ++kk) {
            union { bf16x8 b; unsigned short us[8]; } fr;
            const float4 lo = xv[2 * kk], hi = xv[2 * kk + 1];
            fr.us[0] = (unsigned short)f2bf(lo.x);
            fr.us[1] = (unsigned short)f2bf(lo.y);
            fr.us[2] = (unsigned short)f2bf(lo.z);
            fr.us[3] = (unsigned short)f2bf(lo.w);
            fr.us[4] = (unsigned short)f2bf(hi.x);
            fr.us[5] = (unsigned short)f2bf(hi.y);
            fr.us[6] = (unsigned short)f2bf(hi.z);
            fr.us[7] = (unsigned short)f2bf(hi.w);
            acc = __builtin_amdgcn_mfma_f32_16x16x32_bf16(fr.b, bm2[kk], acc, 0, 0, 0);
        }
        // lane holds D[p = pt*16 + g*4 + q][j = j0 + r]; write fragment-major
        const unsigned addr = (unsigned)((w * 4 + (pt >> 1)) * 1024 +
                                         (((pt & 1) * 2 + (g >> 1)) * 16 + r) * 16 +
                                         (g & 1) * 8);
        uint2 pkt;
        pkt.x = f2bf(acc[0]) | (f2bf(acc[1]) << 16);
        pkt.y = f2bf(acc[2]) | (f2bf(acc[3]) << 16);
        *(uint2*)(lds + addr) = pkt;
    }

    // ---- preload M1 fragments (latency hidden under barrier drain) ----
    bf16x8 am1[4];
    #pragma unroll
    for (int kk = 0; kk < 4; ++kk)
        am1[kk] = *(const bf16x8*)(M1 + (size_t)(i0 + r) * 128 + kk * 32 + g * 8);

    __syncthreads();

    // ---- Stage B: out[i][j] = sum_p M1[i][p] * Tt[j][p] ----
    const int j = (tid & 15);       // placeholder to keep r naming clear below
    (void)j;
    #pragma unroll
    for (int jt = 0; jt < 9; ++jt) {
        f32x4 acc = {0.f, 0.f, 0.f, 0.f};
        #pragma unroll
        for (int kk = 0; kk < 4; ++kk) {
            bf16x8 b = *(const bf16x8*)(lds + (jt * 4 + kk) * 1024 + lane * 16);
            acc = __builtin_amdgcn_mfma_f32_16x16x32_bf16(am1[kk], b, acc, 0, 0, 0);
        }
        const int jc = jt * 16 + r;
        if (jc < NH) {
            #pragma unroll
            for (int q = 0; q < 4; ++q) {
                const int i = i0 + g * 4 + q;
                if (i < NH) os[(size_t)i * NH + jc] = acc[q];
            }
        }
    }
}

extern "C" void kernel_launch(void* const* d_in, const int* in_sizes, int n_in,
                              void* d_out, int out_size, void* d_ws, size_t ws_size,
                              hipStream_t stream) {
    const float* x  = (const float*)d_in[0];
    const float* rw = (const float*)d_in[1];
    float* outp = (float*)d_out;
    unsigned short* M1 = (unsigned short*)d_ws;     // 144*128 bf16
    unsigned short* M2 = M1 + NP * 128;             // 144*128 bf16 (73.7 KB total)

    prep_M<<<dim3(2 * NP), dim3(128), 0, stream>>>(rw, M1, M2);
    dct_resize<<<dim3(NSLICE), dim3(NT), 0, stream>>>(x, M1, M2, outp);
}

// Round 8
// 107.561 us; speedup vs baseline: 1.8947x; 1.8947x over previous
//
#include <hip/hip_runtime.h>
#include <hip/hip_bf16.h>
#include <math.h>

#define NSLICE 2048
#define NH 133     // output spatial size (int(128*1+4)+1)
#define NP 144     // padded to 9 tiles of 16
#define NT 576     // 9 waves per block

// LDS map (69632 B total, 2 blocks/CU):
//   [0, 36864)      Tt (bf16 fragment-major, 36 KB)  -- aliased early by:
//     [0,16384)     fp32 panel buf 0
//     [16384,32768) fp32 panel buf 1
//   [36864, 69632)  X_fm: bf16 X, fragment-major, 32 KB
#define XFM   36864
#define LDSB  69632

typedef __attribute__((ext_vector_type(8))) short bf16x8;   // 8 bf16 = 4 VGPRs
typedef __attribute__((ext_vector_type(4))) float f32x4;

typedef __attribute__((address_space(3))) unsigned int  lds_u32;
typedef const __attribute__((address_space(1))) unsigned int glb_u32;

#define GLOAD_LDS16(gsrc, ldst) \
    __builtin_amdgcn_global_load_lds((glb_u32*)(gsrc), (lds_u32*)(ldst), 16, 0, 0)

#define VM_WAIT2 asm volatile("s_waitcnt vmcnt(2)" ::: "memory")
#define VM_WAIT0 asm volatile("s_waitcnt vmcnt(0)" ::: "memory")
#define LGKM0    asm volatile("s_waitcnt lgkmcnt(0)" ::: "memory")
#define BARRAW() do { __builtin_amdgcn_s_barrier(); __builtin_amdgcn_sched_barrier(0); } while (0)

__device__ __forceinline__ unsigned f2bf(float f) {
    __hip_bfloat16 h = __float2bfloat16(f);   // round-to-nearest-even
    union { __hip_bfloat16 b; unsigned short u; } c; c.b = h; return (unsigned)c.u;
}

// ---------------------------------------------------------------------------
// prep_M: combined (IDCT * mask * DCT) matrices, bf16, in workspace.
//   M[row, p] = sum_{u=0}^{127} D2[u,row] * mask[u] * D1[u,p]
// Rows >= 133 are zero padding. M1 uses rate_weights[0], M2 uses [1].
// ---------------------------------------------------------------------------
__global__ void prep_M(const float* __restrict__ rw,
                       unsigned short* __restrict__ M1,
                       unsigned short* __restrict__ M2) {
    int b   = blockIdx.x;        // 0..287
    int m   = b / NP;            // 0 -> M1 (vertical), 1 -> M2 (horizontal)
    int row = b - m * NP;        // 0..143 (output index i or j)
    int p   = threadIdx.x;       // 0..127 (input index)
    unsigned short* M = (m == 0) ? M1 : M2;

    float val = 0.0f;
    if (row < NH) {
        float r = rw[m];
        float minr = fmaxf((1.0f - 4.0f) / 128.0f, 0.0f);
        r = fminf(fmaxf(r, minr), 2.0f);
        float crop = 128.0f * r;

        const float c1  = (float)(M_PI / 256.0);   // D1 phase period 512
        const float c2  = (float)(M_PI / 266.0);   // D2 phase period 532
        const float s1n = 0.125f;                  // sqrt(2/128)
        const float s10 = 0.08838834764831844f;
        const float s2n = 0.12262786485246718f;    // sqrt(2/133)
        const float s20 = 0.08671099951921386f;

        int tp = 2 * p + 1;
        int ti = 2 * row + 1;
        float acc = 0.0f;
        for (int u = 0; u < 128; ++u) {
            float mask = fminf(fmaxf((4.0f + crop - (float)u) * 0.25f, 0.0f), 1.0f);
            int a1 = (tp * u) & 511;
            int a2 = (ti * u) % 532;
            float d1 = cosf((float)a1 * c1) * ((u == 0) ? s10 : s1n);
            float d2 = cosf((float)a2 * c2) * ((u == 0) ? s20 : s2n);
            acc = fmaf(d1 * mask, d2, acc);
        }
        val = acc;
    }
    M[row * 128 + p] = (unsigned short)f2bf(val);
}

// ---------------------------------------------------------------------------
// dct_resize: one 576-thread block (9 waves) per (b,c) slice.
//   1) X staged in 4 fp32 panels (32 rows, 16 KB) via async global_load_lds,
//      double-buffered; per-lane global source pre-swizzled (slot ^= row&7)
//      so the later LDS reads are bank-conflict-free. Counted vmcnt waits --
//      next panel's loads stay in flight across the convert (no full drain
//      until the last panel).
//   2) convert pass: each X value converted fp32->bf16 ONCE, written to X_fm
//      in fragment-major layout: frag (pt,kk) at (pt*4+kk)*1024 + lane*16.
//   3) Stage A: wave w owns j-tile w; A-frags = contiguous b128 from X_fm;
//      bm2 reg-resident; writes Tt fragment-major (R7-verified mapping).
//   4) Stage B: wave w owns i-tile w; am1 reg-resident; Tt b128 reads
//      lane-contiguous (conflict-free, R7-verified); guarded stores.
// ---------------------------------------------------------------------------
__global__ __launch_bounds__(NT, 5) void dct_resize(
        const float* __restrict__ x,
        const unsigned short* __restrict__ M1,
        const unsigned short* __restrict__ M2,
        float* __restrict__ out) {
    __shared__ __align__(16) unsigned char lds[LDSB];

    const int tid  = threadIdx.x;
    const int w    = tid >> 6;      // wave 0..8
    const int lane = tid & 63;
    const int r    = lane & 15;     // fragment row/col index
    const int g    = lane >> 4;     // k-group 0..3

    const float* xs = x + (size_t)blockIdx.x * (128 * 128);
    float*       os = out + (size_t)blockIdx.x * (NH * NH);

    const int j0 = w * 16;          // stage A: this wave's j-tile
    const int i0 = w * 16;          // stage B: this wave's i-tile

    // ---- preload loop-invariant matrix fragments (once per block) ----
    bf16x8 bm2[4], am1[4];
    #pragma unroll
    for (int kk = 0; kk < 4; ++kk) {
        bm2[kk] = *(const bf16x8*)(M2 + (size_t)(j0 + r) * 128 + kk * 32 + g * 8);
        am1[kk] = *(const bf16x8*)(M1 + (size_t)(i0 + r) * 128 + kk * 32 + g * 8);
    }

    // ---- async panel staging: wave w (<8) owns chunks 2w, 2w+1 (1 KB each)
    // chunk c covers panel rows 2c, 2c+1; lane's 16B: row = 2c + (lane>>5),
    // global slot = (lane&31) ^ (row&7)  (pre-swizzle; LDS dest is linear)
    const int c_lo   = w * 2;
    const int rowip0 = c_lo * 2 + (lane >> 5);      // rows for chunk c_lo
    const int rowip1 = rowip0 + 2;                  // rows for chunk c_lo+1
    const int slot0  = (lane & 31) ^ (rowip0 & 7);
    const int slot1  = (lane & 31) ^ (rowip1 & 7);

    #define ISSUE_PANEL(pan, buf)                                              \
        if (w < 8) {                                                           \
            const float* g0 = xs + (size_t)((pan) * 32 + rowip0) * 128 + slot0 * 4; \
            const float* g1 = xs + (size_t)((pan) * 32 + rowip1) * 128 + slot1 * 4; \
            GLOAD_LDS16(g0, lds + (buf) * 16384 + c_lo * 1024);                \
            GLOAD_LDS16(g1, lds + (buf) * 16384 + (c_lo + 1) * 1024);          \
        }

    ISSUE_PANEL(0, 0);
    ISSUE_PANEL(1, 1);

    // ---- panel loop: wait(counted) -> barrier -> convert -> barrier -> issue
    #pragma unroll
    for (int a = 0; a < 4; ++a) {
        if (a < 3) { VM_WAIT2; } else { VM_WAIT0; }
        BARRAW();

        // convert panel a -> X_fm (512 workers; each emits one b128)
        if (tid < 512) {
            const int fl  = tid >> 6;            // fragment-local 0..7
            const int ll  = tid & 63;
            const int rr  = ll & 15;
            const int gg  = ll >> 4;
            const int kk  = fl & 3;
            const int ptl = fl >> 2;             // 0..1
            const int row = ptl * 16 + rr;       // row within panel
            const int key = rr & 7;
            const int u0  = kk * 8 + gg * 2;     // global 16B slot of first half
            const unsigned char* pb = lds + (a & 1) * 16384 + row * 512;
            const float4 va = *(const float4*)(pb + ((u0)     ^ key) * 16);
            const float4 vb = *(const float4*)(pb + ((u0 + 1) ^ key) * 16);
            uint4 pkt;
            pkt.x = f2bf(va.x) | (f2bf(va.y) << 16);
            pkt.y = f2bf(va.z) | (f2bf(va.w) << 16);
            pkt.z = f2bf(vb.x) | (f2bf(vb.y) << 16);
            pkt.w = f2bf(vb.z) | (f2bf(vb.w) << 16);
            *(uint4*)(lds + XFM + (a * 8 + fl) * 1024 + ll * 16) = pkt;
        }
        LGKM0;
        BARRAW();
        if (a == 0) ISSUE_PANEL(2, 0);
        if (a == 1) ISSUE_PANEL(3, 1);
    }
    // X_fm complete and visible; panel buffers dead -> Tt may use [0,36864)

    // ---- Stage A: Tt[j][p] = sum_q X[p][q] * M2[j][q] ----
    #pragma unroll
    for (int pt = 0; pt < 8; ++pt) {
        f32x4 acc = {0.f, 0.f, 0.f, 0.f};
        #pragma unroll
        for (int kk = 0; kk < 4; ++kk) {
            bf16x8 a = *(const bf16x8*)(lds + XFM + (pt * 4 + kk) * 1024 + lane * 16);
            acc = __builtin_amdgcn_mfma_f32_16x16x32_bf16(a, bm2[kk], acc, 0, 0, 0);
        }
        // lane holds D[p = pt*16 + g*4 + q][j = j0 + r]; fragment-major Tt
        const unsigned addr = (unsigned)((w * 4 + (pt >> 1)) * 1024 +
                                         (((pt & 1) * 2 + (g >> 1)) * 16 + r) * 16 +
                                         (g & 1) * 8);
        uint2 pkt;
        pkt.x = f2bf(acc[0]) | (f2bf(acc[1]) << 16);
        pkt.y = f2bf(acc[2]) | (f2bf(acc[3]) << 16);
        *(uint2*)(lds + addr) = pkt;
    }
    LGKM0;
    BARRAW();

    // ---- Stage B: out[i][j] = sum_p M1[i][p] * Tt[j][p] ----
    #pragma unroll
    for (int jt = 0; jt < 9; ++jt) {
        f32x4 acc = {0.f, 0.f, 0.f, 0.f};
        #pragma unroll
        for (int kk = 0; kk < 4; ++kk) {
            bf16x8 b = *(const bf16x8*)(lds + (jt * 4 + kk) * 1024 + lane * 16);
            acc = __builtin_amdgcn_mfma_f32_16x16x32_bf16(am1[kk], b, acc, 0, 0, 0);
        }
        const int jc = jt * 16 + r;
        if (jc < NH) {
            #pragma unroll
            for (int q = 0; q < 4; ++q) {
                const int i = i0 + g * 4 + q;
                if (i < NH) os[(size_t)i * NH + jc] = acc[q];
            }
        }
    }
}

extern "C" void kernel_launch(void* const* d_in, const int* in_sizes, int n_in,
                              void* d_out, int out_size, void* d_ws, size_t ws_size,
                              hipStream_t stream) {
    const float* x  = (const float*)d_in[0];
    const float* rw = (const float*)d_in[1];
    float* outp = (float*)d_out;
    unsigned short* M1 = (unsigned short*)d_ws;     // 144*128 bf16
    unsigned short* M2 = M1 + NP * 128;             // 144*128 bf16 (73.7 KB total)

    prep_M<<<dim3(2 * NP), dim3(128), 0, stream>>>(rw, M1, M2);
    dct_resize<<<dim3(NSLICE), dim3(NT), 0, stream>>>(x, M1, M2, outp);
}

// Round 9
// 105.321 us; speedup vs baseline: 1.9350x; 1.0213x over previous
//
#include <hip/hip_runtime.h>
#include <hip/hip_bf16.h>
#include <math.h>

#define NSLICE 2048
#define NH 133     // output spatial size (int(128*1+4)+1)
#define NP 144     // padded to 9 tiles of 16
#define NT 576     // 9 waves per block
#define SPB 4      // slices per block
#define NBLK (NSLICE / SPB)     // 512 blocks = exactly 2/CU, zero turnover
#define PANELS (SPB * 8)        // 32 16-row panels per block

// LDS map (69632 B, 2 blocks/CU):
//   [0, 32768)      4 x 8KB fp32 panel buffers (16 rows x 512 B, swizzled)
//   [32768, 69632)  Tt bf16 fragment-major (36 KB)
#define TTB  32768
#define LDSB 69632

typedef __attribute__((ext_vector_type(8))) short bf16x8;   // 8 bf16 = 4 VGPRs
typedef __attribute__((ext_vector_type(4))) float f32x4;

typedef __attribute__((address_space(3))) unsigned int  lds_u32;
typedef const __attribute__((address_space(1))) unsigned int glb_u32;

#define GLOAD_LDS16(gsrc, ldst) \
    __builtin_amdgcn_global_load_lds((glb_u32*)(gsrc), (lds_u32*)(ldst), 16, 0, 0)

#define VMW0  asm volatile("s_waitcnt vmcnt(0)" ::: "memory")
#define VMW1  asm volatile("s_waitcnt vmcnt(1)" ::: "memory")
#define VMW2  asm volatile("s_waitcnt vmcnt(2)" ::: "memory")
#define VMW38 asm volatile("s_waitcnt vmcnt(38)" ::: "memory")
// barrier: drain LDS ops, raw s_barrier, fence compiler motion both sides.
// vmcnt deliberately NOT drained -- panels stay in flight across barriers.
#define BAR() do { __builtin_amdgcn_sched_barrier(0); \
                   asm volatile("s_waitcnt lgkmcnt(0)" ::: "memory"); \
                   __builtin_amdgcn_s_barrier(); \
                   __builtin_amdgcn_sched_barrier(0); } while (0)

__device__ __forceinline__ unsigned f2bf(float f) {
    __hip_bfloat16 h = __float2bfloat16(f);   // round-to-nearest-even
    union { __hip_bfloat16 b; unsigned short u; } c; c.b = h; return (unsigned)c.u;
}

// ---------------------------------------------------------------------------
// prep_M: combined (IDCT * mask * DCT) matrices, bf16, in workspace.
//   M[row, p] = sum_{u=0}^{127} D2[u,row] * mask[u] * D1[u,p]
// Cosines via LDS tables (phase is integer mod 512 / mod 532).
// ---------------------------------------------------------------------------
__global__ void prep_M(const float* __restrict__ rw,
                       unsigned short* __restrict__ M1,
                       unsigned short* __restrict__ M2) {
    __shared__ float t1[512];
    __shared__ float t2[532];
    const int b   = blockIdx.x;        // 0..287
    const int m   = b / NP;            // 0 -> M1, 1 -> M2
    const int row = b - m * NP;        // 0..143
    const int p   = threadIdx.x;       // 0..127

    const float c1  = (float)(M_PI / 256.0);
    const float c2  = (float)(M_PI / 266.0);
    const float s1n = 0.125f;                  // sqrt(2/128)
    const float s10 = 0.08838834764831844f;    // s1n/sqrt(2)
    const float s2n = 0.12262786485246718f;    // sqrt(2/133)
    const float s20 = 0.08671099951921386f;    // s2n/sqrt(2)

    for (int k = p; k < 512; k += 128) t1[k] = cosf((float)k * c1) * s1n;
    for (int k = p; k < 532; k += 128) t2[k] = cosf((float)k * c2) * s2n;
    __syncthreads();

    unsigned short* M = (m == 0) ? M1 : M2;
    float val = 0.0f;
    if (row < NH) {
        float r = rw[m];
        float minr = fmaxf((1.0f - 4.0f) / 128.0f, 0.0f);
        r = fminf(fmaxf(r, minr), 2.0f);
        const float crop = 128.0f * r;

        const int tp = 2 * p + 1;
        const int ti = 2 * row + 1;
        float acc = s10 * s20;        // u = 0 term (mask(0) == 1 since crop >= 0)
        int a1 = 0, a2 = 0;
        for (int u = 1; u < 128; ++u) {
            a1 = (a1 + tp) & 511;
            a2 += ti; if (a2 >= 532) a2 -= 532;
            float mask = fminf(fmaxf((4.0f + crop - (float)u) * 0.25f, 0.0f), 1.0f);
            acc = fmaf(t1[a1] * mask, t2[a2], acc);
        }
        val = acc;
    }
    M[row * 128 + p] = (unsigned short)f2bf(val);
}

// ---------------------------------------------------------------------------
// dct_resize: 512 resident blocks (2/CU), 9 waves, 4 slices each.
// Continuous pipeline: 32 16-row fp32 panels stream through 4 LDS buffers
// via global_load_lds, issue-ahead-3, counted vmcnt (never a mid-loop full
// drain) -- loads stay in flight across barriers, stage B, and slice
// boundaries. Stage A reads fp32 fragments directly from the panel (per-row
// bit-interleave swizzle -> exactly 2 lanes/bank-slot = free), converts to
// bf16 in registers, MFMAs vs reg-resident bm2, writes Tt fragment-major
// (R7/R8-verified mapping). Stage B: reg-resident am1, lane-contiguous Tt
// reads (conflict-free), guarded stores.
// vmcnt bookkeeping (in-order queue): panels only, except right after
// stage B where 36 stores/wave sit between panels 2 and 3 of the next
// slice -> waits of 38 for those two panels.
// ---------------------------------------------------------------------------
__global__ __launch_bounds__(NT, 5) void dct_resize(
        const float* __restrict__ x,
        const unsigned short* __restrict__ M1,
        const unsigned short* __restrict__ M2,
        float* __restrict__ out) {
    __shared__ __align__(16) unsigned char lds[LDSB];

    const int tid  = threadIdx.x;
    const int w    = tid >> 6;      // wave 0..8
    const int lane = tid & 63;
    const int r    = lane & 15;     // fragment row/col index
    const int g    = lane >> 4;     // k-group 0..3

    const float* xbase = x   + (size_t)blockIdx.x * SPB * (128 * 128);
    float*       obase = out + (size_t)blockIdx.x * SPB * (NH * NH);

    const int j0 = w * 16;          // stage A: this wave's j-tile
    const int i0 = w * 16;          // stage B: this wave's i-tile

    // ---- preload loop-invariant matrix fragments; fence so the compiler's
    // waitcnt for them lands HERE (before any panel issue), keeping the
    // panel vmcnt queue clean ----
    bf16x8 bm2[4], am1[4];
    #pragma unroll
    for (int kk = 0; kk < 4; ++kk) {
        bm2[kk] = *(const bf16x8*)(M2 + (size_t)(j0 + r) * 128 + kk * 32 + g * 8);
        am1[kk] = *(const bf16x8*)(M1 + (size_t)(i0 + r) * 128 + kk * 32 + g * 8);
    }
    asm volatile("" :: "v"(bm2[0]), "v"(bm2[1]), "v"(bm2[2]), "v"(bm2[3]),
                       "v"(am1[0]), "v"(am1[1]), "v"(am1[2]), "v"(am1[3]));

    // ---- panel loader mapping (512 threads; 1 gload_lds of 16B each) ----
    // LDS dest is linear: buf + tid*16 (wave-uniform base + lane*16).
    // Global source pre-swizzled: slot u = l ^ tau(row),
    // tau(row) = (row&1) | (((row>>1)&3)<<3)  -- bit-interleave.
    const int prow  = tid >> 5;                                   // 0..15
    const int pslot = (tid & 31) ^ ((prow & 1) | (((prow >> 1) & 3) << 3));

    #define ISSUE(n) do { if (w < 8) {                                         \
        const float* _src = xbase + (size_t)((n) >> 3) * (128 * 128)           \
                          + (size_t)(((n) & 7) * 16 + prow) * 128 + pslot * 4; \
        GLOAD_LDS16(_src, lds + ((n) & 3) * 8192 + tid * 16); } } while (0)

    ISSUE(0); ISSUE(1); ISSUE(2);

    const int key = (r & 1) | (((r >> 1) & 3) << 3);   // stage-A read swizzle

    for (int s = 0; s < SPB; ++s) {
        #pragma unroll
        for (int a = 0; a < 8; ++a) {
            const int n = s * 8 + a;
            // ---- wait for panel n (counted; see header comment) ----
            if (a == 0)               { if (s == 0) VMW2; /* else: done pre-stageB */ }
            else if (a == 1 || a == 2){ if (s == 0) VMW2; else VMW38; }
            else if (a == 6)          { if (s == SPB - 1) VMW1; else VMW2; }
            else if (a == 7)          { if (s == SPB - 1) VMW0; else VMW2; }
            else                      { VMW2; }
            BAR();
            if (n + 3 < PANELS) ISSUE(n + 3);

            // ---- Stage A on panel n: Tt[j][p] for p-tile a ----
            const unsigned char* pb = lds + (n & 3) * 8192 + r * 512;
            f32x4 acc = {0.f, 0.f, 0.f, 0.f};
            #pragma unroll
            for (int kk = 0; kk < 4; ++kk) {
                const int u0 = kk * 8 + g * 2;
                const float4 lo = *(const float4*)(pb + ((u0)     ^ key) * 16);
                const float4 hi = *(const float4*)(pb + ((u0 + 1) ^ key) * 16);
                union { bf16x8 b; unsigned short us[8]; } fr;
                fr.us[0] = (unsigned short)f2bf(lo.x);
                fr.us[1] = (unsigned short)f2bf(lo.y);
                fr.us[2] = (unsigned short)f2bf(lo.z);
                fr.us[3] = (unsigned short)f2bf(lo.w);
                fr.us[4] = (unsigned short)f2bf(hi.x);
                fr.us[5] = (unsigned short)f2bf(hi.y);
                fr.us[6] = (unsigned short)f2bf(hi.z);
                fr.us[7] = (unsigned short)f2bf(hi.w);
                acc = __builtin_amdgcn_mfma_f32_16x16x32_bf16(fr.b, bm2[kk], acc, 0, 0, 0);
            }
            // lane holds D[p = a*16 + g*4 + q][j = j0 + r]; fragment-major Tt
            const unsigned taddr = TTB + (unsigned)((w * 4 + (a >> 1)) * 1024 +
                                   (((a & 1) * 2 + (g >> 1)) * 16 + r) * 16 +
                                   (g & 1) * 8);
            uint2 pkt;
            pkt.x = f2bf(acc[0]) | (f2bf(acc[1]) << 16);
            pkt.y = f2bf(acc[2]) | (f2bf(acc[3]) << 16);
            *(uint2*)(lds + taddr) = pkt;
        }

        VMW2;    // next slice's panel 0 arrived (last slice: trivially passes)
        BAR();   // Tt complete & visible

        // ---- Stage B: out[i][j] = sum_p M1[i][p] * Tt[j][p] (36 stores) ----
        float* os = obase + (size_t)s * (NH * NH);
        #pragma unroll
        for (int jt = 0; jt < 9; ++jt) {
            f32x4 acc = {0.f, 0.f, 0.f, 0.f};
            #pragma unroll
            for (int kk = 0; kk < 4; ++kk) {
                bf16x8 bfr = *(const bf16x8*)(lds + TTB + (jt * 4 + kk) * 1024 + lane * 16);
                acc = __builtin_amdgcn_mfma_f32_16x16x32_bf16(am1[kk], bfr, acc, 0, 0, 0);
            }
            const int jc = jt * 16 + r;
            if (jc < NH) {
                #pragma unroll
                for (int q = 0; q < 4; ++q) {
                    const int i = i0 + g * 4 + q;
                    if (i < NH) os[(size_t)i * NH + jc] = acc[q];
                }
            }
        }
        // top-of-next-slice BAR() separates stage-B Tt reads from the next
        // stage-A Tt writes.
    }
    #undef ISSUE
}

extern "C" void kernel_launch(void* const* d_in, const int* in_sizes, int n_in,
                              void* d_out, int out_size, void* d_ws, size_t ws_size,
                              hipStream_t stream) {
    const float* x  = (const float*)d_in[0];
    const float* rw = (const float*)d_in[1];
    float* outp = (float*)d_out;
    unsigned short* M1 = (unsigned short*)d_ws;     // 144*128 bf16
    unsigned short* M2 = M1 + NP * 128;             // 144*128 bf16 (73.7 KB total)

    prep_M<<<dim3(2 * NP), dim3(128), 0, stream>>>(rw, M1, M2);
    dct_resize<<<dim3(NBLK), dim3(NT), 0, stream>>>(x, M1, M2, outp);
}

// Round 10
// 76.321 us; speedup vs baseline: 2.6702x; 1.3800x over previous
//
#include <hip/hip_runtime.h>
#include <hip/hip_bf16.h>
#include <math.h>

#define NSLICE 2048
#define NH 133     // output spatial size (int(128*1+4)+1)
#define NP 144     // padded to 9 tiles of 16
#define NT 576     // 9 waves per block

// LDS map (78,848 B; x2 = 157,696 <= 160 KiB -> 2 blocks/CU):
//   [0, 32768)       X_fm   : 32 frags (pt*4+kk) x 1024 B, bf16 fragment-major
//   [32768, 69632)   M1_fm  : 36 frags (it*4+kk) x 1024 B, bf16 fragment-major
//   [69632, 78848)   scratch: 9 waves x 1024 B (per-wave repack, reused per kk)
#define M1B  32768
#define SCR  69632
#define LDSB 78848

typedef __attribute__((ext_vector_type(8))) short bf16x8;   // 8 bf16 = 4 VGPRs
typedef __attribute__((ext_vector_type(4))) float f32x4;

typedef __attribute__((address_space(3))) unsigned int  lds_u32;
typedef const __attribute__((address_space(1))) unsigned int glb_u32;

#define GLOAD_LDS16(gsrc, ldst) \
    __builtin_amdgcn_global_load_lds((glb_u32*)(gsrc), (lds_u32*)(ldst), 16, 0, 0)

__device__ __forceinline__ unsigned f2bf(float f) {
    __hip_bfloat16 h = __float2bfloat16(f);   // round-to-nearest-even
    union { __hip_bfloat16 b; unsigned short u; } c; c.b = h; return (unsigned)c.u;
}

// ---------------------------------------------------------------------------
// prep_M: combined (IDCT * mask * DCT) matrices, bf16, in workspace.
//   M[row, p] = sum_{u=0}^{127} D2[u,row] * mask[u] * D1[u,p]
// M1 is emitted FRAGMENT-MAJOR (ready for MFMA A-fragment copy to LDS):
//   frag (it = row>>4, kk = p>>5), ushort index
//   (it*4+kk)*512 + (((p>>3)&3)*16 + (row&15))*8 + (p&7)
// M2 stays row-major (per-wave register fragments read it directly).
// ---------------------------------------------------------------------------
__global__ void prep_M(const float* __restrict__ rw,
                       unsigned short* __restrict__ M1,
                       unsigned short* __restrict__ M2) {
    __shared__ float t1[512];
    __shared__ float t2[532];
    const int b   = blockIdx.x;        // 0..287
    const int m   = b / NP;            // 0 -> M1, 1 -> M2
    const int row = b - m * NP;        // 0..143
    const int p   = threadIdx.x;       // 0..127

    const float c1  = (float)(M_PI / 256.0);
    const float c2  = (float)(M_PI / 266.0);
    const float s1n = 0.125f;                  // sqrt(2/128)
    const float s10 = 0.08838834764831844f;    // s1n/sqrt(2)
    const float s2n = 0.12262786485246718f;    // sqrt(2/133)
    const float s20 = 0.08671099951921386f;    // s2n/sqrt(2)

    for (int k = p; k < 512; k += 128) t1[k] = cosf((float)k * c1) * s1n;
    for (int k = p; k < 532; k += 128) t2[k] = cosf((float)k * c2) * s2n;
    __syncthreads();

    float val = 0.0f;
    if (row < NH) {
        float r = rw[m];
        float minr = fmaxf((1.0f - 4.0f) / 128.0f, 0.0f);
        r = fminf(fmaxf(r, minr), 2.0f);
        const float crop = 128.0f * r;

        const int tp = 2 * p + 1;
        const int ti = 2 * row + 1;
        float acc = s10 * s20;        // u = 0 term (mask(0) == 1 since crop >= 0)
        int a1 = 0, a2 = 0;
        for (int u = 1; u < 128; ++u) {
            a1 = (a1 + tp) & 511;
            a2 += ti; if (a2 >= 532) a2 -= 532;
            float mask = fminf(fmaxf((4.0f + crop - (float)u) * 0.25f, 0.0f), 1.0f);
            acc = fmaf(t1[a1] * mask, t2[a2], acc);
        }
        val = acc;
    }
    const unsigned short v16 = (unsigned short)f2bf(val);
    if (m == 0) {
        const int it = row >> 4, rr = row & 15;
        const int k2 = p >> 5, gg = (p >> 3) & 3, e = p & 7;
        M1[(size_t)((it * 4 + k2) * 512 + (gg * 16 + rr) * 8 + e)] = v16;
    } else {
        M2[(size_t)row * 128 + p] = v16;
    }
}

// ---------------------------------------------------------------------------
// dct_resize: one 576-thread block (9 waves) per (b,c) slice, ONE barrier.
//   staging (pre-barrier):
//     - M1_fm -> LDS via async global_load_lds (4 x 16B per thread)
//     - bm2: per-wave M2 register fragments (j-tile w)
//     - X: waves 0-7 read 32B/lane contiguous fp32, cvt, write X_fm
//       fragment-major (lane*16 -> conflict-clean, full-line consumption)
//   post-barrier (waves fully independent, no more syncs):
//     Stage A: wave w owns j-tile w: T[j0+r][p] via 32 MFMA, X_fm reads
//     repack : per-wave 1KB scratch, per-kk (R4-verified seg mapping;
//              in-wave DS ordering makes it barrier-free)
//     Stage B: out[:, j0+r] via 36 MFMA, M1_fm lane*16 reads; guarded stores
// ---------------------------------------------------------------------------
__global__ __launch_bounds__(NT, 5) void dct_resize(
        const float* __restrict__ x,
        const unsigned short* __restrict__ M1f,
        const unsigned short* __restrict__ M2,
        float* __restrict__ out) {
    __shared__ __align__(16) unsigned char lds[LDSB];

    const int tid  = threadIdx.x;
    const int w    = tid >> 6;      // wave 0..8
    const int lane = tid & 63;
    const int r    = lane & 15;     // fragment row/col index
    const int g    = lane >> 4;     // k-group 0..3

    const float* xs = x + (size_t)blockIdx.x * (128 * 128);
    float*       os = out + (size_t)blockIdx.x * (NH * NH);

    const int j0 = w * 16;          // this wave's output-column tile

    // ---- async copy M1_fm -> LDS (36,864 B = 576 threads x 4 x 16 B) ----
    #pragma unroll
    for (int v = 0; v < 4; ++v)
        GLOAD_LDS16(M1f + (size_t)(v * NT + tid) * 8,
                    lds + M1B + (v * NT + tid) * 16);

    // ---- per-wave M2 register fragments (L2-hot) ----
    bf16x8 bm2[4];
    #pragma unroll
    for (int kk = 0; kk < 4; ++kk)
        bm2[kk] = *(const bf16x8*)(M2 + (size_t)(j0 + r) * 128 + kk * 32 + g * 8);

    // ---- X staging: waves 0-7, 4 frags each; 32 contiguous B per lane ----
    if (w < 8) {
        #pragma unroll
        for (int v = 0; v < 4; ++v) {
            const int f  = v * 8 + w;        // fragment id 0..31
            const int pt = f >> 2, k2 = f & 3;
            const float* src = xs + (size_t)(pt * 16 + r) * 128 + k2 * 32 + g * 8;
            const float4 lo = *(const float4*)src;
            const float4 hi = *(const float4*)(src + 4);
            uint4 pkt;
            pkt.x = f2bf(lo.x) | (f2bf(lo.y) << 16);
            pkt.y = f2bf(lo.z) | (f2bf(lo.w) << 16);
            pkt.z = f2bf(hi.x) | (f2bf(hi.y) << 16);
            pkt.w = f2bf(hi.z) | (f2bf(hi.w) << 16);
            *(uint4*)(lds + f * 1024 + lane * 16) = pkt;
        }
    }
    __syncthreads();   // the ONLY barrier (drains vmcnt for gload_lds too)

    // ---- Stage A: T[j0+r][p] = sum_q X[p][q] * M2[j0+r][q] ----
    uint2 u2[8];
    #pragma unroll
    for (int pt = 0; pt < 8; ++pt) {
        f32x4 acc = {0.f, 0.f, 0.f, 0.f};
        #pragma unroll
        for (int kk = 0; kk < 4; ++kk) {
            bf16x8 a = *(const bf16x8*)(lds + (pt * 4 + kk) * 1024 + lane * 16);
            acc = __builtin_amdgcn_mfma_f32_16x16x32_bf16(a, bm2[kk], acc, 0, 0, 0);
        }
        // lane holds T[j0+r][pt*16 + g*4 + q], q = 0..3 (D layout)
        u2[pt].x = f2bf(acc[0]) | (f2bf(acc[1]) << 16);
        u2[pt].y = f2bf(acc[2]) | (f2bf(acc[3]) << 16);
    }

    // ---- per-wave repack: D layout (4-consec p) -> B-fragment (8-consec p)
    // seg s of the kk-window holds T[j0+r][ p = 32kk + 4s .. +3 ] at r*8.
    // write: acc[2kk] -> seg g, acc[2kk+1] -> seg 4+g; read segs 2g, 2g+1.
    // In-wave DS ops are processed in order -> no barrier needed (R4-proven).
    unsigned char* scr = lds + SCR + w * 1024;
    bf16x8 bfrag[4];
    #pragma unroll
    for (int kk = 0; kk < 4; ++kk) {
        *(uint2*)(scr + (g)     * 128 + r * 8) = u2[2 * kk];
        *(uint2*)(scr + (4 + g) * 128 + r * 8) = u2[2 * kk + 1];
        const uint2 lo2 = *(const uint2*)(scr + (2 * g)     * 128 + r * 8);
        const uint2 hi2 = *(const uint2*)(scr + (2 * g + 1) * 128 + r * 8);
        union { uint4 u; bf16x8 b; } cv;
        cv.u = make_uint4(lo2.x, lo2.y, hi2.x, hi2.y);
        bfrag[kk] = cv.b;
    }

    // ---- Stage B: out[i][j0+r] = sum_p M1[i][p] * T[j0+r][p] ----
    const int jc = j0 + r;
    #pragma unroll
    for (int it = 0; it < 9; ++it) {
        f32x4 acc = {0.f, 0.f, 0.f, 0.f};
        #pragma unroll
        for (int kk = 0; kk < 4; ++kk) {
            bf16x8 a = *(const bf16x8*)(lds + M1B + (it * 4 + kk) * 1024 + lane * 16);
            acc = __builtin_amdgcn_mfma_f32_16x16x32_bf16(a, bfrag[kk], acc, 0, 0, 0);
        }
        if (jc < NH) {
            #pragma unroll
            for (int q = 0; q < 4; ++q) {
                const int i = it * 16 + g * 4 + q;
                if (i < NH) os[(size_t)i * NH + jc] = acc[q];
            }
        }
    }
}

extern "C" void kernel_launch(void* const* d_in, const int* in_sizes, int n_in,
                              void* d_out, int out_size, void* d_ws, size_t ws_size,
                              hipStream_t stream) {
    const float* x  = (const float*)d_in[0];
    const float* rw = (const float*)d_in[1];
    float* outp = (float*)d_out;
    unsigned short* M1 = (unsigned short*)d_ws;     // 18432 ushorts, fragment-major
    unsigned short* M2 = M1 + 18432;                // 18432 ushorts, row-major

    prep_M<<<dim3(2 * NP), dim3(128), 0, stream>>>(rw, M1, M2);
    dct_resize<<<dim3(NSLICE), dim3(NT), 0, stream>>>(x, M1, M2, outp);
}